// Round 1
// baseline (187.221 us; speedup 1.0000x reference)
//
#include <hip/hip_runtime.h>

// B=2, S=2048, D=1024, H=16, HD=64. K == Q (xk = x@Wq.T, same RoPE).
// Pipeline: f32->bf16 convert -> [GEMM+RoPE -> Q bf16 [B,H,S,64]],
//           [GEMM -> V^T bf16 [B,H,64,S]] -> flash attention (bf16 MFMA).
// ws usage: 28MB.

typedef float f32x4 __attribute__((ext_vector_type(4)));
typedef short s16x8 __attribute__((ext_vector_type(8)));

__device__ inline unsigned short f2bf(float f) {
  union { float f; unsigned u; } v; v.f = f;
  unsigned r = v.u + 0x7FFFu + ((v.u >> 16) & 1u);
  return (unsigned short)(r >> 16);
}

__global__ __launch_bounds__(256) void convert_bf16(
    const float* __restrict__ in, unsigned short* __restrict__ out, int n4) {
  int i = blockIdx.x * blockDim.x + threadIdx.x;
  if (i < n4) {
    float4 v = ((const float4*)in)[i];
    ushort4 o;
    o.x = f2bf(v.x); o.y = f2bf(v.y); o.z = f2bf(v.z); o.w = f2bf(v.w);
    ((ushort4*)out)[i] = o;
  }
}

// out[m][n] = sum_k A[m][k] * W[n][k];  M=4096, N=1024, K=1024 (bf16 in, f32 acc)
// IS_Q: fuse RoPE, write Q[b][h][s][hd] ; else write V^T[b][h][hd][s]
template <int IS_Q>
__global__ __launch_bounds__(256) void qv_gemm(
    const unsigned short* __restrict__ A, const unsigned short* __restrict__ W,
    const float* __restrict__ cosT, const float* __restrict__ sinT,
    unsigned short* __restrict__ Out) {
  __shared__ unsigned short As[128][72];  // pad 8: stride 144B -> conflict-free reads
  __shared__ unsigned short Bs[128][72];
  const int K = 1024;
  int tid = threadIdx.x;
  int bm = blockIdx.x & 31, bn = blockIdx.x >> 5;  // 32 x 8 blocks
  int w = tid >> 6, lane = tid & 63, lr = lane & 15, lg = lane >> 4;
  int wm = w >> 1, wn = w & 1;
  f32x4 acc[4][4] = {};

  for (int kt = 0; kt < K; kt += 64) {
#pragma unroll
    for (int i = 0; i < 4; ++i) {
      int c = tid + 256 * i;
      int r = c >> 3, cc = c & 7;
      *(s16x8*)&As[r][cc * 8] = *(const s16x8*)&A[(bm * 128 + r) * K + kt + cc * 8];
      *(s16x8*)&Bs[r][cc * 8] = *(const s16x8*)&W[(bn * 128 + r) * K + kt + cc * 8];
    }
    __syncthreads();
    s16x8 af[4][2], bfr[4][2];
#pragma unroll
    for (int mf = 0; mf < 4; ++mf)
#pragma unroll
      for (int kk = 0; kk < 2; ++kk)
        af[mf][kk] = *(const s16x8*)&As[wm * 64 + mf * 16 + lr][kk * 32 + lg * 8];
#pragma unroll
    for (int nf = 0; nf < 4; ++nf)
#pragma unroll
      for (int kk = 0; kk < 2; ++kk)
        bfr[nf][kk] = *(const s16x8*)&Bs[wn * 64 + nf * 16 + lr][kk * 32 + lg * 8];
#pragma unroll
    for (int mf = 0; mf < 4; ++mf)
#pragma unroll
      for (int nf = 0; nf < 4; ++nf)
#pragma unroll
        for (int kk = 0; kk < 2; ++kk)
          acc[mf][nf] = __builtin_amdgcn_mfma_f32_16x16x32_bf16(
              af[mf][kk], bfr[nf][kk], acc[mf][nf], 0, 0, 0);
    __syncthreads();
  }

  int mBase = bm * 128 + wm * 64;
  int nBase = bn * 128 + wn * 64;  // 64-aligned: wave spans exactly one head col-block
#pragma unroll
  for (int mf = 0; mf < 4; ++mf)
#pragma unroll
    for (int j = 0; j < 4; ++j) {
      int m = mBase + mf * 16 + 4 * lg + j;
      int b = m >> 11, s = m & 2047;
      if (IS_Q) {
#pragma unroll
        for (int nf = 0; nf < 4; ++nf) {
          int col = nBase + nf * 16 + lr;
          int h = col >> 6, hd = col & 63;
          float self = acc[mf][nf][j];
          float part = (nf < 2) ? -acc[mf][nf + 2][j] : acc[mf][nf - 2][j];
          float val = self * cosT[s * 64 + hd] + part * sinT[s * 64 + hd];
          Out[(((b * 16 + h) * 2048 + s) << 6) + hd] = f2bf(val);
        }
      } else {
#pragma unroll
        for (int nf = 0; nf < 4; ++nf) {
          int col = nBase + nf * 16 + lr;
          int h = col >> 6, hd = col & 63;
          Out[((b * 16 + h) * 64 + hd) * 2048 + s] = f2bf(acc[mf][nf][j]);
        }
      }
    }
}

// Flash attention. Q doubles as K. grid (S/64, B*H), 4 waves/block.
// Wave w owns q-rows [q0+16w, q0+16w+16). Per k-tile: S=QK^T (8 MFMA),
// online softmax (shfl reduce over 16 lanes), P->LDS, PV (8 MFMA).
__global__ __launch_bounds__(256) void attn(
    const unsigned short* __restrict__ Qb,  // [32][2048][64]
    const unsigned short* __restrict__ Vt,  // [32][64][2048]
    float* __restrict__ out) {              // [2][2048][1024]
  __shared__ unsigned short Ks[64][72];
  __shared__ unsigned short Vs[64][72];      // Vs[hd][kcol]
  __shared__ unsigned short Ps[4][16][72];   // per-wave P
  int tid = threadIdx.x;
  int qb = blockIdx.x, bh = blockIdx.y;
  int w = tid >> 6, lane = tid & 63, lr = lane & 15, lg = lane >> 4;
  int q0 = qb * 64;
  const unsigned short* Qh = Qb + bh * (2048 * 64);
  const unsigned short* Vh = Vt + bh * (64 * 2048);

  s16x8 aq[2];
  {
    int qrow = q0 + w * 16 + lr;
    aq[0] = *(const s16x8*)&Qh[qrow * 64 + lg * 8];
    aq[1] = *(const s16x8*)&Qh[qrow * 64 + 32 + lg * 8];
  }
  f32x4 o_[4] = {};
  float m_[4], l_[4];
#pragma unroll
  for (int j = 0; j < 4; ++j) { m_[j] = -1e30f; l_[j] = 0.f; }
  const float SC = 0.125f * 1.44269504088896f;  // scale * log2(e)

  for (int kt = 0; kt <= qb; ++kt) {
    int k0 = kt * 64;
#pragma unroll
    for (int i = 0; i < 2; ++i) {
      int c = tid + 256 * i;
      int r = c >> 3, cc = c & 7;
      *(s16x8*)&Ks[r][cc * 8] = *(const s16x8*)&Qh[(k0 + r) * 64 + cc * 8];
      *(s16x8*)&Vs[r][cc * 8] = *(const s16x8*)&Vh[r * 2048 + k0 + cc * 8];
    }
    __syncthreads();

    f32x4 sa[4] = {};
#pragma unroll
    for (int nf = 0; nf < 4; ++nf)
#pragma unroll
      for (int kk = 0; kk < 2; ++kk) {
        s16x8 bk = *(const s16x8*)&Ks[nf * 16 + lr][kk * 32 + lg * 8];
        sa[nf] = __builtin_amdgcn_mfma_f32_16x16x32_bf16(aq[kk], bk, sa[nf], 0, 0, 0);
      }

    bool diag = (kt == qb);
    float p[4][4];
#pragma unroll
    for (int j = 0; j < 4; ++j) {
      float tm = -1e30f;
#pragma unroll
      for (int nf = 0; nf < 4; ++nf) {
        float sv = sa[nf][j] * SC;
        if (diag) {
          int kcol = k0 + nf * 16 + lr;
          int qr = q0 + w * 16 + 4 * lg + j;
          if (kcol > qr) sv = -1e30f;
        }
        p[nf][j] = sv;
        tm = fmaxf(tm, sv);
      }
#pragma unroll
      for (int d = 1; d < 16; d <<= 1) tm = fmaxf(tm, __shfl_xor(tm, d));
      float mn = fmaxf(m_[j], tm);
      float alpha = exp2f(m_[j] - mn);
      m_[j] = mn;
      float rs = 0.f;
#pragma unroll
      for (int nf = 0; nf < 4; ++nf) {
        float pv = exp2f(p[nf][j] - mn);
        p[nf][j] = pv;
        rs += pv;
      }
#pragma unroll
      for (int d = 1; d < 16; d <<= 1) rs += __shfl_xor(rs, d);
      l_[j] = l_[j] * alpha + rs;
#pragma unroll
      for (int nf = 0; nf < 4; ++nf) o_[nf][j] *= alpha;
    }

#pragma unroll
    for (int nf = 0; nf < 4; ++nf)
#pragma unroll
      for (int j = 0; j < 4; ++j)
        Ps[w][4 * lg + j][nf * 16 + lr] = f2bf(p[nf][j]);

    s16x8 pa[2];
    pa[0] = *(const s16x8*)&Ps[w][lr][lg * 8];
    pa[1] = *(const s16x8*)&Ps[w][lr][32 + lg * 8];
#pragma unroll
    for (int nf = 0; nf < 4; ++nf)
#pragma unroll
      for (int kk = 0; kk < 2; ++kk) {
        s16x8 bv = *(const s16x8*)&Vs[nf * 16 + lr][kk * 32 + lg * 8];
        o_[nf] = __builtin_amdgcn_mfma_f32_16x16x32_bf16(
            kk ? pa[1] : pa[0], bv, o_[nf], 0, 0, 0);
      }
    __syncthreads();
  }

  int b = bh >> 4, h = bh & 15;
#pragma unroll
  for (int nf = 0; nf < 4; ++nf)
#pragma unroll
    for (int j = 0; j < 4; ++j) {
      int s = q0 + w * 16 + 4 * lg + j;
      out[(b * 2048 + s) * 1024 + h * 64 + nf * 16 + lr] = o_[nf][j] / l_[j];
    }
}

extern "C" void kernel_launch(void* const* d_in, const int* in_sizes, int n_in,
                              void* d_out, int out_size, void* d_ws, size_t ws_size,
                              hipStream_t stream) {
  const float* x = (const float*)d_in[0];
  const float* Wq = (const float*)d_in[1];
  const float* Wv = (const float*)d_in[2];
  const float* cosT = (const float*)d_in[3];
  const float* sinT = (const float*)d_in[4];
  float* out = (float*)d_out;

  unsigned short* xb = (unsigned short*)d_ws;        // 4M elems
  unsigned short* wqb = xb + 4 * 1024 * 1024;        // 1M
  unsigned short* wvb = wqb + 1024 * 1024;           // 1M
  unsigned short* Qb = wvb + 1024 * 1024;            // 4M (post-RoPE Q == K)
  unsigned short* Vtb = Qb + 4 * 1024 * 1024;        // 4M (V transposed)

  convert_bf16<<<4096, 256, 0, stream>>>(x, xb, 1048576);
  convert_bf16<<<1024, 256, 0, stream>>>(Wq, wqb, 262144);
  convert_bf16<<<1024, 256, 0, stream>>>(Wv, wvb, 262144);

  qv_gemm<1><<<256, 256, 0, stream>>>(xb, wqb, cosT, sinT, Qb);
  qv_gemm<0><<<256, 256, 0, stream>>>(xb, wvb, cosT, sinT, Vtb);

  attn<<<dim3(32, 32), 256, 0, stream>>>(Qb, Vtb, out);
}

// Round 2
// 113.185 us; speedup vs baseline: 1.6541x; 1.6541x over previous
//
#include <hip/hip_runtime.h>

// B=2, S=2048, D=1024, H=16, HD=64. K == Q (xk = x@Wq.T, same RoPE).
// Pipeline: f32->bf16 convert -> [GEMM+RoPE -> Q bf16 [B,H,S,64]],
//           [GEMM -> V^T bf16 [B,H,64,S]] -> flash attention (bf16 MFMA).
// Attn: paired q-tiles (p, 31-p) per block, dbuf K/V LDS, reg prefetch,
//       defer-max softmax with lane-partial l (no per-tile shfl).

typedef float f32x4 __attribute__((ext_vector_type(4)));
typedef short s16x8 __attribute__((ext_vector_type(8)));

__device__ inline unsigned short f2bf(float f) {
  union { float f; unsigned u; } v; v.f = f;
  unsigned r = v.u + 0x7FFFu + ((v.u >> 16) & 1u);
  return (unsigned short)(r >> 16);
}

__global__ __launch_bounds__(256) void convert_bf16(
    const float* __restrict__ in, unsigned short* __restrict__ out, int n4) {
  int i = blockIdx.x * blockDim.x + threadIdx.x;
  if (i < n4) {
    float4 v = ((const float4*)in)[i];
    ushort4 o;
    o.x = f2bf(v.x); o.y = f2bf(v.y); o.z = f2bf(v.z); o.w = f2bf(v.w);
    ((ushort4*)out)[i] = o;
  }
}

// out[m][n] = sum_k A[m][k] * W[n][k];  M=4096, N=1024, K=1024 (bf16 in, f32 acc)
// IS_Q: fuse RoPE, write Q[b][h][s][hd] ; else write V^T[b][h][hd][s]
template <int IS_Q>
__global__ __launch_bounds__(256) void qv_gemm(
    const unsigned short* __restrict__ A, const unsigned short* __restrict__ W,
    const float* __restrict__ cosT, const float* __restrict__ sinT,
    unsigned short* __restrict__ Out) {
  __shared__ unsigned short As[128][72];
  __shared__ unsigned short Bs[128][72];
  const int K = 1024;
  int tid = threadIdx.x;
  int bm = blockIdx.x & 31, bn = blockIdx.x >> 5;
  int w = tid >> 6, lane = tid & 63, lr = lane & 15, lg = lane >> 4;
  int wm = w >> 1, wn = w & 1;
  f32x4 acc[4][4] = {};

  for (int kt = 0; kt < K; kt += 64) {
#pragma unroll
    for (int i = 0; i < 4; ++i) {
      int c = tid + 256 * i;
      int r = c >> 3, cc = c & 7;
      *(s16x8*)&As[r][cc * 8] = *(const s16x8*)&A[(bm * 128 + r) * K + kt + cc * 8];
      *(s16x8*)&Bs[r][cc * 8] = *(const s16x8*)&W[(bn * 128 + r) * K + kt + cc * 8];
    }
    __syncthreads();
    s16x8 af[4][2], bfr[4][2];
#pragma unroll
    for (int mf = 0; mf < 4; ++mf)
#pragma unroll
      for (int kk = 0; kk < 2; ++kk)
        af[mf][kk] = *(const s16x8*)&As[wm * 64 + mf * 16 + lr][kk * 32 + lg * 8];
#pragma unroll
    for (int nf = 0; nf < 4; ++nf)
#pragma unroll
      for (int kk = 0; kk < 2; ++kk)
        bfr[nf][kk] = *(const s16x8*)&Bs[wn * 64 + nf * 16 + lr][kk * 32 + lg * 8];
#pragma unroll
    for (int mf = 0; mf < 4; ++mf)
#pragma unroll
      for (int nf = 0; nf < 4; ++nf)
#pragma unroll
        for (int kk = 0; kk < 2; ++kk)
          acc[mf][nf] = __builtin_amdgcn_mfma_f32_16x16x32_bf16(
              af[mf][kk], bfr[nf][kk], acc[mf][nf], 0, 0, 0);
    __syncthreads();
  }

  int mBase = bm * 128 + wm * 64;
  int nBase = bn * 128 + wn * 64;
#pragma unroll
  for (int mf = 0; mf < 4; ++mf)
#pragma unroll
    for (int j = 0; j < 4; ++j) {
      int m = mBase + mf * 16 + 4 * lg + j;
      int b = m >> 11, s = m & 2047;
      if (IS_Q) {
#pragma unroll
        for (int nf = 0; nf < 4; ++nf) {
          int col = nBase + nf * 16 + lr;
          int h = col >> 6, hd = col & 63;
          float self = acc[mf][nf][j];
          float part = (nf < 2) ? -acc[mf][nf + 2][j] : acc[mf][nf - 2][j];
          float val = self * cosT[s * 64 + hd] + part * sinT[s * 64 + hd];
          Out[(((b * 16 + h) * 2048 + s) << 6) + hd] = f2bf(val);
        }
      } else {
#pragma unroll
        for (int nf = 0; nf < 4; ++nf) {
          int col = nBase + nf * 16 + lr;
          int h = col >> 6, hd = col & 63;
          Out[((b * 16 + h) * 64 + hd) * 2048 + s] = f2bf(acc[mf][nf][j]);
        }
      }
    }
}

// Flash attention, paired q-tiles. grid (16, B*H), 4 waves/block.
// Block p handles q-tiles qtA=p and qtB=31-p (balanced: 33 steps/block).
// Per k-tile: stage (dbuf, prefetched regs), 1 barrier, per q-tile:
// QK^T (8 MFMA) -> defer-max softmax (lane-partial l) -> P->LDS -> PV (8 MFMA).
__global__ __launch_bounds__(256) void attn(
    const unsigned short* __restrict__ Qb,  // [32][2048][64]
    const unsigned short* __restrict__ Vt,  // [32][64][2048]
    float* __restrict__ out) {              // [2][2048][1024]
  __shared__ unsigned short Ks[2][64][72];
  __shared__ unsigned short Vs[2][64][72];   // Vs[hd][kcol]
  __shared__ unsigned short Ps[4][16][80];   // per-wave P, stride 80 (conflict-free writes)
  const float SC = 0.125f * 1.44269504088896f;  // scale * log2(e)
  int tid = threadIdx.x;
  int pp = blockIdx.x, bh = blockIdx.y;
  int w = tid >> 6, lane = tid & 63, lr = lane & 15, lg = lane >> 4;
  int qtA = pp, qtB = 31 - pp;
  const unsigned short* Qh = Qb + bh * (2048 * 64);
  const unsigned short* Vh = Vt + bh * (64 * 2048);

  s16x8 aqA[2], aqB[2];
  {
    int qr = qtA * 64 + w * 16 + lr;
    aqA[0] = *(const s16x8*)&Qh[qr * 64 + lg * 8];
    aqA[1] = *(const s16x8*)&Qh[qr * 64 + 32 + lg * 8];
    qr = qtB * 64 + w * 16 + lr;
    aqB[0] = *(const s16x8*)&Qh[qr * 64 + lg * 8];
    aqB[1] = *(const s16x8*)&Qh[qr * 64 + 32 + lg * 8];
  }
  f32x4 oA[4] = {}, oB[4] = {};
  float mA[4], lA[4], mB[4], lB[4];
#pragma unroll
  for (int j = 0; j < 4; ++j) { mA[j] = mB[j] = -1e30f; lA[j] = lB[j] = 0.f; }

  int sr[2], sc_[2];
#pragma unroll
  for (int i = 0; i < 2; ++i) {
    int c = tid + 256 * i;
    sr[i] = c >> 3; sc_[i] = (c & 7) * 8;
  }
  // prefetch tile 0
  s16x8 kr[2], vr[2];
#pragma unroll
  for (int i = 0; i < 2; ++i) {
    kr[i] = *(const s16x8*)&Qh[sr[i] * 64 + sc_[i]];
    vr[i] = *(const s16x8*)&Vh[sr[i] * 2048 + sc_[i]];
  }

  int ktmax = qtB;
  for (int kt = 0; kt <= ktmax; ++kt) {
    int bf_ = kt & 1;
#pragma unroll
    for (int i = 0; i < 2; ++i) {
      *(s16x8*)&Ks[bf_][sr[i]][sc_[i]] = kr[i];
      *(s16x8*)&Vs[bf_][sr[i]][sc_[i]] = vr[i];
    }
    if (kt < ktmax) {
      int k0n = (kt + 1) * 64;
#pragma unroll
      for (int i = 0; i < 2; ++i) {
        kr[i] = *(const s16x8*)&Qh[(k0n + sr[i]) * 64 + sc_[i]];
        vr[i] = *(const s16x8*)&Vh[sr[i] * 2048 + k0n + sc_[i]];
      }
    }
    __syncthreads();

    auto step = [&](const s16x8* aq, f32x4* o, float* m_, float* l_, bool diag) {
      f32x4 sa[4] = {};
#pragma unroll
      for (int kk = 0; kk < 2; ++kk)
#pragma unroll
        for (int nf = 0; nf < 4; ++nf) {
          s16x8 bk = *(const s16x8*)&Ks[bf_][nf * 16 + lr][kk * 32 + lg * 8];
          sa[nf] = __builtin_amdgcn_mfma_f32_16x16x32_bf16(aq[kk], bk, sa[nf], 0, 0, 0);
        }
      float tm[4]; float worst = -3e38f;
#pragma unroll
      for (int j = 0; j < 4; ++j) {
        tm[j] = -3e38f;
#pragma unroll
        for (int nf = 0; nf < 4; ++nf) {
          float sv = sa[nf][j] * SC;
          if (diag && (nf * 16 + lr > w * 16 + lg * 4 + j)) sv = -1e30f;
          sa[nf][j] = sv;
          tm[j] = fmaxf(tm[j], sv);
        }
        worst = fmaxf(worst, tm[j] - m_[j]);
      }
      if (!__all(worst <= 8.0f)) {  // rare: rescale path
#pragma unroll
        for (int j = 0; j < 4; ++j) {
          float t = tm[j];
#pragma unroll
          for (int d = 1; d < 16; d <<= 1) t = fmaxf(t, __shfl_xor(t, d));
          float mn = fmaxf(m_[j], t);
          float al = exp2f(m_[j] - mn);
          m_[j] = mn; l_[j] *= al;
#pragma unroll
          for (int nf = 0; nf < 4; ++nf) o[nf][j] *= al;
        }
      }
#pragma unroll
      for (int nf = 0; nf < 4; ++nf)
#pragma unroll
        for (int j = 0; j < 4; ++j) {
          float pv = exp2f(sa[nf][j] - m_[j]);
          l_[j] += pv;  // lane-partial sum; reduced once at the end
          Ps[w][lg * 4 + j][nf * 16 + lr] = f2bf(pv);
        }
      s16x8 pa0 = *(const s16x8*)&Ps[w][lr][lg * 8];
      s16x8 pa1 = *(const s16x8*)&Ps[w][lr][32 + lg * 8];
#pragma unroll
      for (int kk = 0; kk < 2; ++kk)
#pragma unroll
        for (int nf = 0; nf < 4; ++nf) {
          s16x8 bv = *(const s16x8*)&Vs[bf_][nf * 16 + lr][kk * 32 + lg * 8];
          o[nf] = __builtin_amdgcn_mfma_f32_16x16x32_bf16(
              kk ? pa1 : pa0, bv, o[nf], 0, 0, 0);
        }
    };
    if (kt <= qtA) step(aqA, oA, mA, lA, kt == qtA);
    step(aqB, oB, mB, lB, kt == qtB);
  }

  int b = bh >> 4, h = bh & 15;
  float rA[4], rB[4];
#pragma unroll
  for (int j = 0; j < 4; ++j) {
    float t = lA[j];
#pragma unroll
    for (int d = 1; d < 16; d <<= 1) t += __shfl_xor(t, d);
    rA[j] = t;
    t = lB[j];
#pragma unroll
    for (int d = 1; d < 16; d <<= 1) t += __shfl_xor(t, d);
    rB[j] = t;
  }
#pragma unroll
  for (int nf = 0; nf < 4; ++nf)
#pragma unroll
    for (int j = 0; j < 4; ++j) {
      int sA = qtA * 64 + w * 16 + lg * 4 + j;
      out[(b * 2048 + sA) * 1024 + h * 64 + nf * 16 + lr] = oA[nf][j] / rA[j];
      int sB = qtB * 64 + w * 16 + lg * 4 + j;
      out[(b * 2048 + sB) * 1024 + h * 64 + nf * 16 + lr] = oB[nf][j] / rB[j];
    }
}

extern "C" void kernel_launch(void* const* d_in, const int* in_sizes, int n_in,
                              void* d_out, int out_size, void* d_ws, size_t ws_size,
                              hipStream_t stream) {
  const float* x = (const float*)d_in[0];
  const float* Wq = (const float*)d_in[1];
  const float* Wv = (const float*)d_in[2];
  const float* cosT = (const float*)d_in[3];
  const float* sinT = (const float*)d_in[4];
  float* out = (float*)d_out;

  unsigned short* xb = (unsigned short*)d_ws;        // 4M elems
  unsigned short* wqb = xb + 4 * 1024 * 1024;        // 1M
  unsigned short* wvb = wqb + 1024 * 1024;           // 1M
  unsigned short* Qb = wvb + 1024 * 1024;            // 4M (post-RoPE Q == K)
  unsigned short* Vtb = Qb + 4 * 1024 * 1024;        // 4M (V transposed)

  convert_bf16<<<4096, 256, 0, stream>>>(x, xb, 1048576);
  convert_bf16<<<1024, 256, 0, stream>>>(Wq, wqb, 262144);
  convert_bf16<<<1024, 256, 0, stream>>>(Wv, wvb, 262144);

  qv_gemm<1><<<256, 256, 0, stream>>>(xb, wqb, cosT, sinT, Qb);
  qv_gemm<0><<<256, 256, 0, stream>>>(xb, wvb, cosT, sinT, Vtb);

  attn<<<dim3(16, 32), 256, 0, stream>>>(Qb, Vtb, out);
}

// Round 3
// 101.700 us; speedup vs baseline: 1.8409x; 1.1129x over previous
//
#include <hip/hip_runtime.h>

// B=2, S=2048, D=1024, H=16, HD=64. K == Q (xk = x@Wq.T, same RoPE).
// Pipeline: f32->bf16 convert -> [GEMM+RoPE -> Q bf16 [B,H,S,64]],
//           [GEMM -> V^T bf16 [B,H,64,S]] -> flash attention (bf16 MFMA).
// Attn: swapped QK^T (mfma(K,Q)) + sigma-permuted K LDS rows so P lands
//       in-register in PV A-frag layout (cvt_pk packing, no P LDS, no shfl
//       in common path). Paired q-tiles, dbuf K/V, reg prefetch, defer-max.

typedef float f32x4 __attribute__((ext_vector_type(4)));
typedef short s16x8 __attribute__((ext_vector_type(8)));

__device__ inline unsigned short f2bf(float f) {
  union { float f; unsigned u; } v; v.f = f;
  unsigned r = v.u + 0x7FFFu + ((v.u >> 16) & 1u);
  return (unsigned short)(r >> 16);
}

__global__ __launch_bounds__(256) void convert_bf16(
    const float* __restrict__ in, unsigned short* __restrict__ out, int n4) {
  int i = blockIdx.x * blockDim.x + threadIdx.x;
  if (i < n4) {
    float4 v = ((const float4*)in)[i];
    ushort4 o;
    o.x = f2bf(v.x); o.y = f2bf(v.y); o.z = f2bf(v.z); o.w = f2bf(v.w);
    ((ushort4*)out)[i] = o;
  }
}

// out[m][n] = sum_k A[m][k] * W[n][k];  M=4096, N=1024, K=1024 (bf16 in, f32 acc)
// IS_Q: fuse RoPE, write Q[b][h][s][hd] ; else write V^T[b][h][hd][s]
template <int IS_Q>
__global__ __launch_bounds__(256) void qv_gemm(
    const unsigned short* __restrict__ A, const unsigned short* __restrict__ W,
    const float* __restrict__ cosT, const float* __restrict__ sinT,
    unsigned short* __restrict__ Out) {
  __shared__ unsigned short As[128][72];
  __shared__ unsigned short Bs[128][72];
  const int K = 1024;
  int tid = threadIdx.x;
  int bm = blockIdx.x & 31, bn = blockIdx.x >> 5;
  int w = tid >> 6, lane = tid & 63, lr = lane & 15, lg = lane >> 4;
  int wm = w >> 1, wn = w & 1;
  f32x4 acc[4][4] = {};

  for (int kt = 0; kt < K; kt += 64) {
#pragma unroll
    for (int i = 0; i < 4; ++i) {
      int c = tid + 256 * i;
      int r = c >> 3, cc = c & 7;
      *(s16x8*)&As[r][cc * 8] = *(const s16x8*)&A[(bm * 128 + r) * K + kt + cc * 8];
      *(s16x8*)&Bs[r][cc * 8] = *(const s16x8*)&W[(bn * 128 + r) * K + kt + cc * 8];
    }
    __syncthreads();
    s16x8 af[4][2], bfr[4][2];
#pragma unroll
    for (int mf = 0; mf < 4; ++mf)
#pragma unroll
      for (int kk = 0; kk < 2; ++kk)
        af[mf][kk] = *(const s16x8*)&As[wm * 64 + mf * 16 + lr][kk * 32 + lg * 8];
#pragma unroll
    for (int nf = 0; nf < 4; ++nf)
#pragma unroll
      for (int kk = 0; kk < 2; ++kk)
        bfr[nf][kk] = *(const s16x8*)&Bs[wn * 64 + nf * 16 + lr][kk * 32 + lg * 8];
#pragma unroll
    for (int mf = 0; mf < 4; ++mf)
#pragma unroll
      for (int nf = 0; nf < 4; ++nf)
#pragma unroll
        for (int kk = 0; kk < 2; ++kk)
          acc[mf][nf] = __builtin_amdgcn_mfma_f32_16x16x32_bf16(
              af[mf][kk], bfr[nf][kk], acc[mf][nf], 0, 0, 0);
    __syncthreads();
  }

  int mBase = bm * 128 + wm * 64;
  int nBase = bn * 128 + wn * 64;
#pragma unroll
  for (int mf = 0; mf < 4; ++mf)
#pragma unroll
    for (int j = 0; j < 4; ++j) {
      int m = mBase + mf * 16 + 4 * lg + j;
      int b = m >> 11, s = m & 2047;
      if (IS_Q) {
#pragma unroll
        for (int nf = 0; nf < 4; ++nf) {
          int col = nBase + nf * 16 + lr;
          int h = col >> 6, hd = col & 63;
          float self = acc[mf][nf][j];
          float part = (nf < 2) ? -acc[mf][nf + 2][j] : acc[mf][nf - 2][j];
          float val = self * cosT[s * 64 + hd] + part * sinT[s * 64 + hd];
          Out[(((b * 16 + h) * 2048 + s) << 6) + hd] = f2bf(val);
        }
      } else {
#pragma unroll
        for (int nf = 0; nf < 4; ++nf) {
          int col = nBase + nf * 16 + lr;
          int h = col >> 6, hd = col & 63;
          Out[((b * 16 + h) * 64 + hd) * 2048 + s] = f2bf(acc[mf][nf][j]);
        }
      }
    }
}

// Flash attention, swapped-QK layout. flat grid 512, XCD-chunked swizzle.
// Block handles q-tiles qtA=pp, qtB=31-pp (33 steps). Per k-tile:
// stage K (sigma-permuted rows) + V, 1 barrier, per q-tile:
// S^T = mfma(K,Q) -> per-lane softmax (defer-max) -> cvt_pk -> PV.
__global__ __launch_bounds__(256) void attn(
    const unsigned short* __restrict__ Qb,  // [32][2048][64]
    const unsigned short* __restrict__ Vt,  // [32][64][2048]
    float* __restrict__ out) {              // [2][2048][1024]
  __shared__ unsigned short Ks[2][64][72];
  __shared__ unsigned short Vs[2][64][72];   // Vs[hd][kcol]
  const float SC = 0.125f * 1.44269504088896f;  // scale * log2(e)
  const float THR = 44.0f;                      // ~= 8 / SC (raw-domain defer-max)
  int tid = threadIdx.x;
  int fid = blockIdx.x;
  int swz = (fid & 7) * 64 + (fid >> 3);   // 4 bh's per XCD chunk
  int bh = swz >> 4, pp = swz & 15;
  int w = tid >> 6, lane = tid & 63, lr = lane & 15, lg = lane >> 4;
  int qtA = pp, qtB = 31 - pp;
  const unsigned short* Qh = Qb + bh * (2048 * 64);
  const unsigned short* Vh = Vt + bh * (64 * 2048);

  s16x8 aqA[2], aqB[2];
  {
    int qr = qtA * 64 + w * 16 + lr;
    aqA[0] = *(const s16x8*)&Qh[qr * 64 + lg * 8];
    aqA[1] = *(const s16x8*)&Qh[qr * 64 + 32 + lg * 8];
    qr = qtB * 64 + w * 16 + lr;
    aqB[0] = *(const s16x8*)&Qh[qr * 64 + lg * 8];
    aqB[1] = *(const s16x8*)&Qh[qr * 64 + 32 + lg * 8];
  }
  f32x4 oA[4] = {}, oB[4] = {};
  float mA = -1e30f, lA = 0.f, mB = -1e30f, lB = 0.f;
  int qgA = qtA * 64 + w * 16 + lr;
  int qgB = qtB * 64 + w * 16 + lr;

  int sr[2], sc_[2], sg[2];
#pragma unroll
  for (int i = 0; i < 2; ++i) {
    int c = tid + 256 * i;
    int r = c >> 3;
    sr[i] = r; sc_[i] = (c & 7) * 8;
    // sigma(r): LDS row for kcol r so MFMA tile nf = rows [16nf..16nf+15]
    // holds kcols 8*(lr>>2)+(lr&3)+{0,4,32,36}[nf]
    sg[i] = (r & 32) | (((r >> 2) & 1) << 4) | (((r >> 4) & 1) << 3) |
            (((r >> 3) & 1) << 2) | (r & 3);
  }

  s16x8 kr[2], vr[2];
#pragma unroll
  for (int i = 0; i < 2; ++i) {
    kr[i] = *(const s16x8*)&Qh[sr[i] * 64 + sc_[i]];
    vr[i] = *(const s16x8*)&Vh[sr[i] * 2048 + sc_[i]];
  }

  auto step = [&](const s16x8* aq, f32x4* o, float& m_, float& l_,
                  int qglob, bool diag, int bf_, int k0) {
    f32x4 sa[4] = {};
#pragma unroll
    for (int kk = 0; kk < 2; ++kk)
#pragma unroll
      for (int nf = 0; nf < 4; ++nf) {
        s16x8 ak = *(const s16x8*)&Ks[bf_][nf * 16 + lr][kk * 32 + lg * 8];
        sa[nf] = __builtin_amdgcn_mfma_f32_16x16x32_bf16(ak, aq[kk], sa[nf], 0, 0, 0);
      }
    // lane (lr,lg): sa[nf][j] = S[qrow=lr][kcol = k0 + 8*lg + j + {0,4,32,36}[nf]]
    if (diag) {
#pragma unroll
      for (int nf = 0; nf < 4; ++nf) {
        int kc = k0 + 8 * lg + 4 * (nf & 1) + 32 * (nf >> 1);
#pragma unroll
        for (int j = 0; j < 4; ++j)
          if (kc + j > qglob) sa[nf][j] = -3e38f;
      }
    }
    float tm = sa[0][0];
#pragma unroll
    for (int nf = 0; nf < 4; ++nf)
#pragma unroll
      for (int j = 0; j < 4; ++j) tm = fmaxf(tm, sa[nf][j]);
    if (!__all(tm - m_ <= THR)) {  // rare after tile 0
      float rm = fmaxf(tm, __shfl_xor(tm, 16));
      rm = fmaxf(rm, __shfl_xor(rm, 32));
      float mn = fmaxf(m_, rm);
      float alpha = exp2f((m_ - mn) * SC);
      m_ = mn; l_ *= alpha;
#pragma unroll
      for (int j = 0; j < 4; ++j) {
        float aj = __shfl(alpha, 4 * lg + j);
#pragma unroll
        for (int nf = 0; nf < 4; ++nf) o[nf][j] *= aj;
      }
    }
    float msc = m_ * SC;
    unsigned cpk[8];
#pragma unroll
    for (int nf = 0; nf < 4; ++nf) {
      float p0 = exp2f(fmaf(sa[nf][0], SC, -msc));
      float p1 = exp2f(fmaf(sa[nf][1], SC, -msc));
      float p2 = exp2f(fmaf(sa[nf][2], SC, -msc));
      float p3 = exp2f(fmaf(sa[nf][3], SC, -msc));
      l_ += (p0 + p1) + (p2 + p3);
      unsigned r0, r1;
      asm("v_cvt_pk_bf16_f32 %0, %1, %2" : "=v"(r0) : "v"(p0), "v"(p1));
      asm("v_cvt_pk_bf16_f32 %0, %1, %2" : "=v"(r1) : "v"(p2), "v"(p3));
      cpk[nf * 2] = r0; cpk[nf * 2 + 1] = r1;
    }
#pragma unroll
    for (int kk = 0; kk < 2; ++kk) {
      union { unsigned u[4]; s16x8 v; } pa;
      pa.u[0] = cpk[4 * kk + 0]; pa.u[1] = cpk[4 * kk + 1];
      pa.u[2] = cpk[4 * kk + 2]; pa.u[3] = cpk[4 * kk + 3];
#pragma unroll
      for (int nf = 0; nf < 4; ++nf) {
        s16x8 bv = *(const s16x8*)&Vs[bf_][nf * 16 + lr][kk * 32 + lg * 8];
        o[nf] = __builtin_amdgcn_mfma_f32_16x16x32_bf16(pa.v, bv, o[nf], 0, 0, 0);
      }
    }
  };

  int ktmax = qtB;
  for (int kt = 0; kt <= ktmax; ++kt) {
    int bf_ = kt & 1;
#pragma unroll
    for (int i = 0; i < 2; ++i) {
      *(s16x8*)&Ks[bf_][sg[i]][sc_[i]] = kr[i];
      *(s16x8*)&Vs[bf_][sr[i]][sc_[i]] = vr[i];
    }
    if (kt < ktmax) {
      int k0n = (kt + 1) * 64;
#pragma unroll
      for (int i = 0; i < 2; ++i) {
        kr[i] = *(const s16x8*)&Qh[(k0n + sr[i]) * 64 + sc_[i]];
        vr[i] = *(const s16x8*)&Vh[sr[i] * 2048 + k0n + sc_[i]];
      }
    }
    __syncthreads();
    int k0 = kt * 64;
    if (kt <= qtA) step(aqA, oA, mA, lA, qgA, kt == qtA, bf_, k0);
    step(aqB, oB, mB, lB, qgB, kt == qtB, bf_, k0);
  }

  int b = bh >> 4, h = bh & 15;
  float tA = lA; tA += __shfl_xor(tA, 16); tA += __shfl_xor(tA, 32);
  float tB = lB; tB += __shfl_xor(tB, 16); tB += __shfl_xor(tB, 32);
  float rAj[4], rBj[4];
#pragma unroll
  for (int j = 0; j < 4; ++j) {
    rAj[j] = __shfl(tA, 4 * lg + j);
    rBj[j] = __shfl(tB, 4 * lg + j);
  }
#pragma unroll
  for (int nf = 0; nf < 4; ++nf)
#pragma unroll
    for (int j = 0; j < 4; ++j) {
      int sA = qtA * 64 + w * 16 + lg * 4 + j;
      out[(b * 2048 + sA) * 1024 + h * 64 + nf * 16 + lr] = oA[nf][j] / rAj[j];
      int sB = qtB * 64 + w * 16 + lg * 4 + j;
      out[(b * 2048 + sB) * 1024 + h * 64 + nf * 16 + lr] = oB[nf][j] / rBj[j];
    }
}

extern "C" void kernel_launch(void* const* d_in, const int* in_sizes, int n_in,
                              void* d_out, int out_size, void* d_ws, size_t ws_size,
                              hipStream_t stream) {
  const float* x = (const float*)d_in[0];
  const float* Wq = (const float*)d_in[1];
  const float* Wv = (const float*)d_in[2];
  const float* cosT = (const float*)d_in[3];
  const float* sinT = (const float*)d_in[4];
  float* out = (float*)d_out;

  unsigned short* xb = (unsigned short*)d_ws;        // 4M elems
  unsigned short* wqb = xb + 4 * 1024 * 1024;        // 1M
  unsigned short* wvb = wqb + 1024 * 1024;           // 1M
  unsigned short* Qb = wvb + 1024 * 1024;            // 4M (post-RoPE Q == K)
  unsigned short* Vtb = Qb + 4 * 1024 * 1024;        // 4M (V transposed)

  convert_bf16<<<4096, 256, 0, stream>>>(x, xb, 1048576);
  convert_bf16<<<1024, 256, 0, stream>>>(Wq, wqb, 262144);
  convert_bf16<<<1024, 256, 0, stream>>>(Wv, wvb, 262144);

  qv_gemm<1><<<256, 256, 0, stream>>>(xb, wqb, cosT, sinT, Qb);
  qv_gemm<0><<<256, 256, 0, stream>>>(xb, wvb, cosT, sinT, Vtb);

  attn<<<512, 256, 0, stream>>>(Qb, Vtb, out);
}